// Round 8
// baseline (84.649 us; speedup 1.0000x reference)
//
#include <hip/hip_runtime.h>
#include <hip/hip_bf16.h>
#include <stdint.h>

typedef __hip_bfloat16 bf16;
typedef float f32x4 __attribute__((ext_vector_type(4)));
typedef short bf16x8 __attribute__((ext_vector_type(8)));

#define NB 16384
#define NA 16
#define ND 512
#define NH 512
#define TR 80  // rows per tile: ~26 tiles/XCD-pair <= 32 CUs -> all resident, no tail

// workspace layout (bytes)
#define W1S_OFF 0u
#define W2S_OFF 8388608u
#define PERM_OFF 16777216u
#define META_OFF 16842752u
// meta ints: [0..15]=cnt, [16..31]=off

__device__ __forceinline__ unsigned short f2b(float x) {
  unsigned int b = __float_as_uint(x);
  return (unsigned short)((b + 0x7FFFu + ((b >> 16) & 1u)) >> 16);  // RNE
}

// async global->LDS, 16B per lane. dest = uniform base + lane*16 (HW); src per-lane.
__device__ __forceinline__ void gl16(const void* g, void* l) {
  __builtin_amdgcn_global_load_lds((const __attribute__((address_space(1))) void*)g,
                                   (__attribute__((address_space(3))) void*)l, 16, 0, 0);
}

// ---------------- meta: hist + scan + scatter, one block, ballot-aggregated ----------------
__global__ __launch_bounds__(1024) void k_meta(const int* __restrict__ act,
                                               int* __restrict__ meta,
                                               int* __restrict__ perm) {
  __shared__ int cnt[16], off[16], cur[16];
  int tid = threadIdx.x;
  int lane = tid & 63;
  unsigned long long below = (lane == 0) ? 0ull : (~0ull >> (64 - lane));
  if (tid < 16) cnt[tid] = 0;
  __syncthreads();
  int av[16];
#pragma unroll
  for (int i = 0; i < 16; ++i) {
    int a = act[tid + (i << 10)] & 15;
    av[i] = a;
    unsigned long long m = ~0ull;
#pragma unroll
    for (int b = 0; b < 4; ++b) {
      unsigned long long bal = __ballot((a >> b) & 1);
      m &= ((a >> b) & 1) ? bal : ~bal;
    }
    int ldr = __ffsll((unsigned long long)m) - 1;
    if (lane == ldr) atomicAdd(&cnt[a], (int)__popcll(m));
  }
  __syncthreads();
  if (tid == 0) {
    int o = 0;
    for (int aa = 0; aa < 16; ++aa) {
      off[aa] = o;
      cur[aa] = o;
      o += cnt[aa];
    }
  }
  __syncthreads();
#pragma unroll
  for (int i = 0; i < 16; ++i) {
    int a = av[i];
    unsigned long long m = ~0ull;
#pragma unroll
    for (int b = 0; b < 4; ++b) {
      unsigned long long bal = __ballot((a >> b) & 1);
      m &= ((a >> b) & 1) ? bal : ~bal;
    }
    int ldr = __ffsll((unsigned long long)m) - 1;
    int rank = (int)__popcll(m & below);
    int base = 0;
    if (lane == ldr) base = atomicAdd(&cur[a], (int)__popcll(m));
    base = __shfl(base, ldr);
    perm[base + rank] = tid + (i << 10);
  }
  if (tid < 16) {
    meta[tid] = cnt[tid];
    meta[16 + tid] = off[tid];
  }
}

// ---------------- prep: W[a][d][h] f32 -> fragment-tiled bf16 ----------------
// blob[(h>>4)*16 + (k>>5)] of 1KB; byte = ((k>>3)&3)*256 + (h&15)*16 + (k&7)*2
__global__ __launch_bounds__(256) void k_prep(const float* __restrict__ W1,
                                              const float* __restrict__ W2,
                                              bf16* __restrict__ W1s,
                                              bf16* __restrict__ W2s) {
  __shared__ float tile[64][65];
  int blk = blockIdx.x;          // 0..2047
  int m = blk >> 6;              // matrix 0..31
  int tl = blk & 63;
  int td = tl >> 3, th = tl & 7;
  const float* src = (m < NA) ? (W1 + (size_t)m * (ND * NH)) : (W2 + (size_t)(m - NA) * (ND * NH));
  char* dstb = (m < NA) ? ((char*)W1s + ((size_t)m << 19)) : ((char*)W2s + ((size_t)(m - NA) << 19));
  int t = threadIdx.x;
  int r = t >> 2, c0 = (t & 3) << 4;
  const float* sp = src + (size_t)(td * 64 + r) * NH + th * 64 + c0;
  float4 v0 = ((const float4*)sp)[0];
  float4 v1 = ((const float4*)sp)[1];
  float4 v2 = ((const float4*)sp)[2];
  float4 v3 = ((const float4*)sp)[3];
  float* tr = &tile[r][c0];
  tr[0] = v0.x; tr[1] = v0.y; tr[2] = v0.z; tr[3] = v0.w;
  tr[4] = v1.x; tr[5] = v1.y; tr[6] = v1.z; tr[7] = v1.w;
  tr[8] = v2.x; tr[9] = v2.y; tr[10] = v2.z; tr[11] = v2.w;
  tr[12] = v3.x; tr[13] = v3.y; tr[14] = v3.z; tr[15] = v3.w;
  __syncthreads();
  int hloc = t >> 2, dc = (t & 3) << 4;
  int h = th * 64 + hloc;
  int K0 = td * 64 + dc;
  union { unsigned short us[16]; uint4 q[2]; } u;
#pragma unroll
  for (int i = 0; i < 16; ++i) u.us[i] = f2b(tile[dc + i][hloc]);
  size_t ab = (size_t)((h >> 4) * 16 + (K0 >> 5)) * 1024 + (size_t)(h & 15) * 16;
  *(uint4*)(dstb + ab + (((K0 >> 3) & 3) << 8)) = u.q[0];
  *(uint4*)(dstb + ab + ((((K0 >> 3) + 1) & 3) << 8)) = u.q[1];
}

// ---------------- fused grouped MLP ----------------
// XCD x (bid&7) owns actions 2x,2x+1. Block: 80-row tile, 8 waves; wave w owns h [w*64,+64).
// LDS: Xs 80KB @0, Wbuf 2x32KB @81920 (per-wave-private 4KB slabs, double-buffered),
// outbuf @147456. Weight stream via global_load_lds dwordx4, counted vmcnt(4), no loop barriers.
__global__ __launch_bounds__(512, 2) void k_main(
    const float* __restrict__ state, const float* __restrict__ b1,
    const float* __restrict__ b2, const float* __restrict__ W3,
    const float* __restrict__ b3, const bf16* __restrict__ W1s,
    const bf16* __restrict__ W2s, const int* __restrict__ perm,
    const int* __restrict__ meta, float* __restrict__ out) {
  extern __shared__ char smem[];
  char* Xs = smem;
  char* Wbuf = smem + 81920;
  float* outbuf = (float*)(smem + 147456);

  int bid = blockIdx.x;
  int xcd = bid & 7, slot = bid >> 3;
  int a0 = xcd << 1;
  int n0 = meta[a0], n1 = meta[a0 + 1];
  int nt0 = (n0 + TR - 1) / TR, nt1 = (n1 + TR - 1) / TR;
  int a, t;
  if (slot < nt0) {
    a = a0; t = slot;
  } else if (slot < nt0 + nt1) {
    a = a0 + 1; t = slot - nt0;
  } else {
    return;
  }
  int rowbase = meta[16 + a] + t * TR;
  int nrows = meta[a] - t * TR;
  nrows = nrows > TR ? TR : nrows;

  int tid = threadIdx.x;
  int lane = tid & 63;
  int w = tid >> 6;
  int l15 = lane & 15, l4 = lane >> 4;

  const char* Wl1 = (const char*)W1s + ((size_t)a << 19) + (w << 16) + (lane << 4);
  const char* Wl2 = (const char*)W2s + ((size_t)a << 19) + (w << 16) + (lane << 4);
  char* slab = Wbuf + (w << 12);  // + buf*32768 + hf*1024

  // prologue: issue L1 ks=0 -> buf0, ks=1 -> buf1 (complete by staging barrier)
#pragma unroll
  for (int s = 0; s < 2; ++s)
#pragma unroll
    for (int hf = 0; hf < 4; ++hf)
      gl16(Wl1 + hf * 16384 + s * 1024, slab + (s << 15) + (hf << 10));

  // ---- stage X tile -> LDS bf16, swizzle byte ^= (row&7)<<4 ----
  {
#pragma unroll
    for (int it = 0; it < 20; ++it) {
      int c = tid + (it << 9);
      int row = c >> 7, chunk = c & 127;
      int gr = (row < nrows) ? perm[rowbase + row] : -1;
      float4 v = make_float4(0.f, 0.f, 0.f, 0.f);
      if (gr >= 0) v = *(const float4*)(state + (size_t)gr * ND + (chunk << 2));
      uint2 pk;
      pk.x = (unsigned)f2b(v.x) | ((unsigned)f2b(v.y) << 16);
      pk.y = (unsigned)f2b(v.z) | ((unsigned)f2b(v.w) << 16);
      *(uint2*)(Xs + row * 1024 + ((chunk << 3) ^ ((row & 7) << 4))) = pk;
    }
  }
  __syncthreads();  // drains vmcnt(0): prologue slabs complete

  uint2 h1p[20];
  bf16x8 Bc[5], Bn[5], Af[4];

  // ---- layer 1: h1 = relu(X @ W1 + b1), [h][b], h1 kept in registers ----
  {
    f32x4 acc[4][5] = {};
#pragma unroll
    for (int bf = 0; bf < 5; ++bf) {
      int b = (bf << 4) + l15;
      Bc[bf] = *(const bf16x8*)(Xs + b * 1024 + ((l4 << 4) ^ ((b & 7) << 4)));
    }
#pragma unroll
    for (int ks = 0; ks < 16; ++ks) {
      asm volatile("s_waitcnt vmcnt(4)" ::: "memory");  // buf[ks&1] landed
      const char* sb = slab + ((ks & 1) << 15) + (lane << 4);
#pragma unroll
      for (int hf = 0; hf < 4; ++hf) Af[hf] = *(const bf16x8*)(sb + (hf << 10));
      if (ks < 15) {
#pragma unroll
        for (int bf = 0; bf < 5; ++bf) {
          int b = (bf << 4) + l15;
          Bn[bf] = *(const bf16x8*)(Xs + b * 1024 + ((((ks + 1) << 6) + (l4 << 4)) ^ ((b & 7) << 4)));
        }
        asm volatile("s_waitcnt lgkmcnt(5)" ::: "memory");  // Af done (Bn outstanding)
      } else {
        asm volatile("s_waitcnt lgkmcnt(0)" ::: "memory");
      }
      __builtin_amdgcn_sched_barrier(0);
      // refill buf[ks&1]: L1 ks+2, or L2 prologue at iters 14/15
      {
        const char* src = (ks < 14) ? (Wl1 + (ks + 2) * 1024) : (Wl2 + (ks - 14) * 1024);
        char* dst = slab + ((ks & 1) << 15);
#pragma unroll
        for (int hf = 0; hf < 4; ++hf) gl16(src + hf * 16384, dst + (hf << 10));
      }
#pragma unroll
      for (int hf = 0; hf < 4; ++hf)
#pragma unroll
        for (int bf = 0; bf < 5; ++bf)
          acc[hf][bf] = __builtin_amdgcn_mfma_f32_16x16x32_bf16(Af[hf], Bc[bf], acc[hf][bf], 0, 0, 0);
#pragma unroll
      for (int bf = 0; bf < 5; ++bf) Bc[bf] = Bn[bf];
    }
    // epilogue: bias + relu + pack bf16 into registers
#pragma unroll
    for (int hf = 0; hf < 4; ++hf) {
      int hb = (w << 6) + (hf << 4) + (l4 << 2);
      float4 bias = *(const float4*)(b1 + (a << 9) + hb);
#pragma unroll
      for (int bf = 0; bf < 5; ++bf) {
        float x0 = fmaxf(acc[hf][bf][0] + bias.x, 0.f);
        float x1 = fmaxf(acc[hf][bf][1] + bias.y, 0.f);
        float x2 = fmaxf(acc[hf][bf][2] + bias.z, 0.f);
        float x3 = fmaxf(acc[hf][bf][3] + bias.w, 0.f);
        h1p[hf * 5 + bf].x = (unsigned)f2b(x0) | ((unsigned)f2b(x1) << 16);
        h1p[hf * 5 + bf].y = (unsigned)f2b(x2) | ((unsigned)f2b(x3) << 16);
      }
    }
  }
  __syncthreads();  // all waves done reading X; drains L2-prologue gloads (complete)
#pragma unroll
  for (int hf = 0; hf < 4; ++hf) {
    int hb2 = ((w << 6) + (hf << 4) + (l4 << 2)) << 1;
#pragma unroll
    for (int bf = 0; bf < 5; ++bf) {
      int b = (bf << 4) + l15;
      *(uint2*)(Xs + b * 1024 + (hb2 ^ ((b & 7) << 4))) = h1p[hf * 5 + bf];
    }
  }
  __syncthreads();

  // ---- layer 2 + fused layer 3: out = relu(h1 @ W2 + b2) . W3 + b3 ----
  {
    f32x4 acc[4][5] = {};
#pragma unroll
    for (int bf = 0; bf < 5; ++bf) {
      int b = (bf << 4) + l15;
      Bc[bf] = *(const bf16x8*)(Xs + b * 1024 + ((l4 << 4) ^ ((b & 7) << 4)));
    }
#pragma unroll
    for (int ks = 0; ks < 16; ++ks) {
      if (ks == 15) {
        asm volatile("s_waitcnt vmcnt(0)" ::: "memory");
      } else {
        asm volatile("s_waitcnt vmcnt(4)" ::: "memory");
      }
      const char* sb = slab + ((ks & 1) << 15) + (lane << 4);
#pragma unroll
      for (int hf = 0; hf < 4; ++hf) Af[hf] = *(const bf16x8*)(sb + (hf << 10));
      if (ks < 15) {
#pragma unroll
        for (int bf = 0; bf < 5; ++bf) {
          int b = (bf << 4) + l15;
          Bn[bf] = *(const bf16x8*)(Xs + b * 1024 + ((((ks + 1) << 6) + (l4 << 4)) ^ ((b & 7) << 4)));
        }
        asm volatile("s_waitcnt lgkmcnt(5)" ::: "memory");
      } else {
        asm volatile("s_waitcnt lgkmcnt(0)" ::: "memory");
      }
      __builtin_amdgcn_sched_barrier(0);
      if (ks < 14) {
        const char* src = Wl2 + (ks + 2) * 1024;
        char* dst = slab + ((ks & 1) << 15);
#pragma unroll
        for (int hf = 0; hf < 4; ++hf) gl16(src + hf * 16384, dst + (hf << 10));
      }
#pragma unroll
      for (int hf = 0; hf < 4; ++hf)
#pragma unroll
        for (int bf = 0; bf < 5; ++bf)
          acc[hf][bf] = __builtin_amdgcn_mfma_f32_16x16x32_bf16(Af[hf], Bc[bf], acc[hf][bf], 0, 0, 0);
#pragma unroll
      for (int bf = 0; bf < 5; ++bf) Bc[bf] = Bn[bf];
    }
    float part[5] = {0.f, 0.f, 0.f, 0.f, 0.f};
#pragma unroll
    for (int hf = 0; hf < 4; ++hf) {
      int hb = (w << 6) + (hf << 4) + (l4 << 2);
      float4 bias = *(const float4*)(b2 + (a << 9) + hb);
      float4 w3v = *(const float4*)(W3 + (a << 9) + hb);
#pragma unroll
      for (int bf = 0; bf < 5; ++bf) {
        part[bf] += fmaxf(acc[hf][bf][0] + bias.x, 0.f) * w3v.x +
                    fmaxf(acc[hf][bf][1] + bias.y, 0.f) * w3v.y +
                    fmaxf(acc[hf][bf][2] + bias.z, 0.f) * w3v.z +
                    fmaxf(acc[hf][bf][3] + bias.w, 0.f) * w3v.w;
      }
    }
#pragma unroll
    for (int bf = 0; bf < 5; ++bf) {
      float p = part[bf];
      p += __shfl_xor(p, 16);
      p += __shfl_xor(p, 32);
      if (l4 == 0) outbuf[w * TR + (bf << 4) + l15] = p;
    }
  }
  __syncthreads();
  if (tid < nrows) {
    float s = b3[a];
#pragma unroll
    for (int ww = 0; ww < 8; ++ww) s += outbuf[ww * TR + tid];
    out[perm[rowbase + tid]] = s;
  }
}

extern "C" void kernel_launch(void* const* d_in, const int* in_sizes, int n_in,
                              void* d_out, int out_size, void* d_ws, size_t ws_size,
                              hipStream_t stream) {
  const float* state = (const float*)d_in[0];
  const float* W1 = (const float*)d_in[1];
  const float* b1 = (const float*)d_in[2];
  const float* W2 = (const float*)d_in[3];
  const float* b2 = (const float*)d_in[4];
  const float* W3 = (const float*)d_in[5];
  const float* b3 = (const float*)d_in[6];
  const int* actions = (const int*)d_in[7];
  float* out = (float*)d_out;
  char* ws = (char*)d_ws;
  bf16* W1s = (bf16*)(ws + W1S_OFF);
  bf16* W2s = (bf16*)(ws + W2S_OFF);
  int* perm = (int*)(ws + PERM_OFF);
  int* meta = (int*)(ws + META_OFF);

  k_meta<<<1, 1024, 0, stream>>>(actions, meta, perm);
  k_prep<<<2048, 256, 0, stream>>>(W1, W2, W1s, W2s);
  hipFuncSetAttribute((const void*)k_main, hipFuncAttributeMaxDynamicSharedMemorySize, 150016);
  k_main<<<512, 512, 150016, stream>>>(state, b1, b2, W3, b3, W1s, W2s, perm, meta, out);
}